// Round 16
// baseline (363.336 us; speedup 1.0000x reference)
//
#include <hip/hip_runtime.h>
#include <hip/hip_bf16.h>
#include <hip/hip_fp16.h>

typedef float f32x4 __attribute__((ext_vector_type(4)));
typedef short s16x8 __attribute__((ext_vector_type(8)));
typedef unsigned int u32x4 __attribute__((ext_vector_type(4)));

#define F_IN 256
#define F_OUT 64
#define KSPLIT 13
#define HBLK 120

static __device__ __forceinline__ short f2bf(float f){  // RTNE
  union { float f; unsigned u; } x; x.f = f;
  unsigned r = (x.u + 0x7FFFu + ((x.u >> 16) & 1u)) >> 16;
  return (short)r;
}

static __device__ __forceinline__ unsigned pack_rtne(float f0, float f1){
  return ((unsigned)(unsigned short)f2bf(f0)) | ((unsigned)(unsigned short)f2bf(f1) << 16);
}

// truncation pack (bias cancels in L2-normalize downstream of the mask GEMM)
static __device__ __forceinline__ unsigned pack_trunc(float f0, float f1){
  return (__float_as_uint(f0) >> 16) | (__float_as_uint(f1) & 0xFFFF0000u);
}

static __device__ __forceinline__ float bf_lo(unsigned u){ return __uint_as_float(u << 16); }
static __device__ __forceinline__ float bf_hi(unsigned u){ return __uint_as_float(u & 0xFFFF0000u); }
static __device__ __forceinline__ float h16(unsigned u){   // fp16 in high16 -> f32
  return __half2float(__ushort_as_half((unsigned short)(u >> 16)));
}

union FragU { u32x4 u; s16x8 s; };

// ---------------- WT transpose-cast ----------------

__global__ void wt_kernel(const float* __restrict__ W, short* __restrict__ WT){
  int idx = blockIdx.x * blockDim.x + threadIdx.x;
  if (idx < 5 * 64 * 256){
    int k = idx & 255, c = (idx >> 8) & 63, by = idx >> 14;
    WT[idx] = f2bf(W[(size_t)(by * 256 + k) * 64 + c]);
  }
}

// ---------------- histogram: single pass, packed LDS bins (lo16=col, hi16=row) ----------------
// per-block count <= ceil(E/HBLK)=5334 < 2^16. NO global atomics: coalesced blkcntP store only.

__global__ __launch_bounds__(1024) void hist_kernel(const int* __restrict__ ei, int E,
                                                    unsigned* __restrict__ blkcntP, int n){
  __shared__ unsigned bins[10240];   // 40 KB
  int tid = threadIdx.x;
  int per = (E + HBLK - 1) / HBLK;
  int e0 = blockIdx.x * per, e1 = min(E, e0 + per);

  for (int i = tid; i < n; i += 1024) bins[i] = 0u;
  __syncthreads();
  for (int e = e0 + tid; e < e1; e += 1024){
    int r = ei[e], c = ei[E + e];
    if (r != c){
      atomicAdd(&bins[c], 1u);
      atomicAdd(&bins[r], 0x10000u);
    }
  }
  __syncthreads();
  for (int i = tid; i < n; i += 1024)
    blkcntP[(size_t)blockIdx.x * n + i] = bins[i];
}

// ---------------- per-bin totals from blkcntP (coalesced; plain stores) ----------------

__global__ void sumcnt_kernel(const unsigned* __restrict__ blkcntP,
                              int* __restrict__ counts, int* __restrict__ deg, int n){
  int bin = blockIdx.x * blockDim.x + threadIdx.x;
  if (bin >= n) return;
  int cc = 0, rc = 0;
  #pragma unroll 8
  for (int blk = 0; blk < HBLK; ++blk){
    unsigned v = blkcntP[(size_t)blk * n + bin];
    cc += (int)(v & 0xFFFFu);
    rc += (int)(v >> 16);
  }
  counts[bin] = cc;
  deg[bin] = rc;
}

// ---------------- scan (wave-shuffle, 4 barriers) + dis/selfnorm ----------------

__global__ __launch_bounds__(1024) void scan_kernel(const int* __restrict__ counts,
                                                    const int* __restrict__ deg,
                                                    float* __restrict__ dis,
                                                    float* __restrict__ selfnorm,
                                                    int* __restrict__ offsets, int n){
  const int C = 10;
  __shared__ int vals[10240];   // 40 KB
  __shared__ int wsums[16];
  int tid = threadIdx.x, wid = tid >> 6, lane = tid & 63;
  for (int i = tid; i < 10240; i += 1024) vals[i] = (i < n) ? counts[i] : 0;
  for (int i = tid; i < n; i += 1024){
    float d = (float)(deg[i] + 1);   // +1: appended self-loop
    dis[i] = rsqrtf(d);
    selfnorm[i] = 1.0f / d;
  }
  __syncthreads();
  int base = tid * C;
  int s = 0;
  #pragma unroll
  for (int i = 0; i < C; ++i) s += vals[base + i];
  int x = s;
  #pragma unroll
  for (int off = 1; off < 64; off <<= 1){
    int y = __shfl_up(x, off);
    if (lane >= off) x += y;
  }
  if (lane == 63) wsums[wid] = x;
  __syncthreads();
  if (wid == 0){
    int v = (lane < 16) ? wsums[lane] : 0;
    int xx = v;
    #pragma unroll
    for (int off = 1; off < 16; off <<= 1){
      int y = __shfl_up(xx, off);
      if (lane >= off) xx += y;
    }
    if (lane < 16) wsums[lane] = xx - v;   // exclusive wave prefix
  }
  __syncthreads();
  int run = (x - s) + wsums[wid];          // exclusive thread prefix
  if (tid == 1023) offsets[n] = run + s;   // grand total
  #pragma unroll
  for (int i = 0; i < C; ++i){ int v = vals[base + i]; vals[base + i] = run; run += v; }
  __syncthreads();
  for (int i = tid; i < 10240; i += 1024)
    if (i < n) offsets[i] = vals[i];
}

// ---------------- per-(block,bin) base positions (unrolled: 8 loads in flight) ----------------

__global__ void blkbase_kernel(const int* __restrict__ offsets, const unsigned* __restrict__ blkcntP,
                               int* __restrict__ blkbase, int n){
  int bin = blockIdx.x * blockDim.x + threadIdx.x;
  if (bin >= n) return;
  int run = offsets[bin];
  #pragma unroll 8
  for (int blk = 0; blk < HBLK; ++blk){
    blkbase[(size_t)blk * n + bin] = run;
    run += (int)(blkcntP[(size_t)blk * n + bin] & 0xFFFFu);
  }
}

// ---------------- fill via LDS cursors (zero global atomics) ----------------
// packed CSR entry: row (u16) | fp16(norm) << 16. Edge ranges match hist_kernel.

__global__ __launch_bounds__(1024) void fill_kernel(const int* __restrict__ ei, int E,
                                                    const float* __restrict__ dis,
                                                    const int* __restrict__ blkbase,
                                                    unsigned* __restrict__ csr, int n){
  __shared__ int bins[10240];   // 40 KB
  int tid = threadIdx.x;
  int per = (E + HBLK - 1) / HBLK;
  int e0 = blockIdx.x * per, e1 = min(E, e0 + per);
  for (int i = tid; i < n; i += 1024) bins[i] = blkbase[(size_t)blockIdx.x * n + i];
  __syncthreads();
  for (int e = e0 + tid; e < e1; e += 1024){
    int r = ei[e], c = ei[E + e];
    if (r == c) continue;
    int pos = atomicAdd(&bins[c], 1);
    unsigned h = (unsigned)__half_as_ushort(__float2half(dis[r] * dis[c]));
    csr[pos] = (unsigned)r | (h << 16);
  }
}

// ---------------- feature GEMM: 5 waves/block, X-strip staged to LDS once ----------------

__global__ __launch_bounds__(320) void fgemm_kernel(const float* __restrict__ X0,
                                                    const float* __restrict__ X1,
                                                    const short* __restrict__ WT,
                                                    float* __restrict__ Yc0,
                                                    unsigned* __restrict__ YcB,
                                                    short* __restrict__ t0bf, int M){
  __shared__ float Xs[16][260];
  int tid = threadIdx.x;
  int w = tid >> 6, l = tid & 63, lr = l & 15, g = l >> 4;
  int row0 = blockIdx.x * 16, bz = blockIdx.y;
  const float* X = bz ? X1 : X0;
  for (int i = tid; i < 1024; i += 320){
    int r = i >> 6, c4 = (i & 63) << 2;
    *(f32x4*)&Xs[r][c4] = *(const f32x4*)(X + (size_t)(row0 + r) * F_IN + c4);
  }
  __syncthreads();

  s16x8 afr[8];
  #pragma unroll
  for (int it = 0; it < 8; ++it){
    f32x4 x0 = *(const f32x4*)&Xs[lr][it * 32 + g * 8];
    f32x4 x1 = *(const f32x4*)&Xs[lr][it * 32 + g * 8 + 4];
    FragU af;
    af.u[0] = pack_rtne(x0[0], x0[1]); af.u[1] = pack_rtne(x0[2], x0[3]);
    af.u[2] = pack_rtne(x1[0], x1[1]); af.u[3] = pack_rtne(x1[2], x1[3]);
    afr[it] = af.s;
  }

  int by = w;   // wave = slab
  f32x4 acc[4];
  #pragma unroll
  for (int ct = 0; ct < 4; ++ct) acc[ct] = (f32x4){0,0,0,0};
  const s16x8* bp[4];
  #pragma unroll
  for (int ct = 0; ct < 4; ++ct)
    bp[ct] = (const s16x8*)(WT + ((size_t)by * 64 + ct * 16 + lr) * F_IN + g * 8);
  #pragma unroll
  for (int it = 0; it < 8; ++it)
    #pragma unroll
    for (int ct = 0; ct < 4; ++ct)
      acc[ct] = __builtin_amdgcn_mfma_f32_16x16x32_bf16(afr[it], bp[ct][it * 4], acc[ct], 0, 0, 0);

  if (by == 0){
    float* yp = Yc0 + (size_t)bz * 64;
    #pragma unroll
    for (int ct = 0; ct < 4; ++ct)
      #pragma unroll
      for (int i = 0; i < 4; ++i)
        yp[(size_t)(row0 + g * 4 + i) * 128 + ct * 16 + lr] = acc[ct][i];
  } else if (by <= 3){
    unsigned* yb = YcB + (size_t)(by - 1) * (M >> 1) * 128 + (size_t)bz * 64;
    #pragma unroll
    for (int ct = 0; ct < 4; ++ct)
      #pragma unroll
      for (int i = 0; i < 4; i += 2){
        int grow = row0 + g * 4 + i;   // even
        yb[(size_t)(grow >> 1) * 128 + ct * 16 + lr] = pack_rtne(acc[ct][i], acc[ct][i + 1]);
      }
  } else {
    short* tb = t0bf + (size_t)bz * 64;
    #pragma unroll
    for (int ct = 0; ct < 4; ++ct)
      #pragma unroll
      for (int i = 0; i < 4; ++i)
        tb[(size_t)(row0 + g * 4 + i) * 128 + ct * 16 + lr] = f2bf(acc[ct][i]);
  }
}

// ---------------- sparse propagate (bf16 messages, packed CSR): tout = Yk + A * tin ----------------

__global__ __launch_bounds__(256) void gather_kernel(const void* __restrict__ Yk,
    const unsigned* __restrict__ tinb, const int* __restrict__ offsets,
    const unsigned* __restrict__ csr, const float* __restrict__ selfnorm,
    unsigned* __restrict__ toutb, float* __restrict__ toutf, int n, int wantf, int ykbf){
  int wid = threadIdx.x >> 6, lane = threadIdx.x & 63;
  int node = blockIdx.x * 4 + wid;
  if (node >= n) return;
  int e0 = offsets[node], e1 = offsets[node + 1];
  float sn = selfnorm[node];
  unsigned t0 = tinb[(size_t)node * 64 + lane];
  float ykx, yky;
  if (ykbf){
    const unsigned* yp = (const unsigned*)Yk + (size_t)(node >> 1) * 128 + lane * 2;
    unsigned u0 = yp[0], u1 = yp[1];
    if (node & 1){ ykx = bf_hi(u0); yky = bf_hi(u1); }
    else         { ykx = bf_lo(u0); yky = bf_lo(u1); }
  } else {
    float2 yk = ((const float2*)Yk)[(size_t)node * 64 + lane];
    ykx = yk.x; yky = yk.y;
  }
  float ax = ykx + sn * bf_lo(t0);
  float ay = yky + sn * bf_hi(t0);
  int i = e0;
  for (; i + 8 <= e1; i += 8){
    unsigned q0 = csr[i],   q1 = csr[i+1], q2 = csr[i+2], q3 = csr[i+3];
    unsigned q4 = csr[i+4], q5 = csr[i+5], q6 = csr[i+6], q7 = csr[i+7];
    unsigned v0 = tinb[(size_t)(q0 & 0xFFFFu) * 64 + lane];
    unsigned v1 = tinb[(size_t)(q1 & 0xFFFFu) * 64 + lane];
    unsigned v2 = tinb[(size_t)(q2 & 0xFFFFu) * 64 + lane];
    unsigned v3 = tinb[(size_t)(q3 & 0xFFFFu) * 64 + lane];
    unsigned v4 = tinb[(size_t)(q4 & 0xFFFFu) * 64 + lane];
    unsigned v5 = tinb[(size_t)(q5 & 0xFFFFu) * 64 + lane];
    unsigned v6 = tinb[(size_t)(q6 & 0xFFFFu) * 64 + lane];
    unsigned v7 = tinb[(size_t)(q7 & 0xFFFFu) * 64 + lane];
    float w0 = h16(q0), w1 = h16(q1), w2 = h16(q2), w3 = h16(q3);
    float w4 = h16(q4), w5 = h16(q5), w6 = h16(q6), w7 = h16(q7);
    ax += w0 * bf_lo(v0); ay += w0 * bf_hi(v0);
    ax += w1 * bf_lo(v1); ay += w1 * bf_hi(v1);
    ax += w2 * bf_lo(v2); ay += w2 * bf_hi(v2);
    ax += w3 * bf_lo(v3); ay += w3 * bf_hi(v3);
    ax += w4 * bf_lo(v4); ay += w4 * bf_hi(v4);
    ax += w5 * bf_lo(v5); ay += w5 * bf_hi(v5);
    ax += w6 * bf_lo(v6); ay += w6 * bf_hi(v6);
    ax += w7 * bf_lo(v7); ay += w7 * bf_hi(v7);
  }
  for (; i + 4 <= e1; i += 4){
    unsigned q0 = csr[i], q1 = csr[i+1], q2 = csr[i+2], q3 = csr[i+3];
    unsigned v0 = tinb[(size_t)(q0 & 0xFFFFu) * 64 + lane];
    unsigned v1 = tinb[(size_t)(q1 & 0xFFFFu) * 64 + lane];
    unsigned v2 = tinb[(size_t)(q2 & 0xFFFFu) * 64 + lane];
    unsigned v3 = tinb[(size_t)(q3 & 0xFFFFu) * 64 + lane];
    float w0 = h16(q0), w1 = h16(q1), w2 = h16(q2), w3 = h16(q3);
    ax += w0 * bf_lo(v0); ay += w0 * bf_hi(v0);
    ax += w1 * bf_lo(v1); ay += w1 * bf_hi(v1);
    ax += w2 * bf_lo(v2); ay += w2 * bf_hi(v2);
    ax += w3 * bf_lo(v3); ay += w3 * bf_hi(v3);
  }
  for (; i < e1; ++i){
    unsigned q = csr[i];
    float w = h16(q);
    unsigned v = tinb[(size_t)(q & 0xFFFFu) * 64 + lane];
    ax += w * bf_lo(v); ay += w * bf_hi(v);
  }
  if (wantf){
    float2 r; r.x = ax; r.y = ay;
    ((float2*)toutf)[(size_t)node * 64 + lane] = r;
  } else {
    toutb[(size_t)node * 64 + lane] = pack_rtne(ax, ay);
  }
}

// ---------------- relu + split + LDS-transpose bf16 pack ----------------

__global__ __launch_bounds__(256) void relu_trans_kernel(const float* __restrict__ u,
    float* __restrict__ emb, float* __restrict__ emb_a, short* __restrict__ embBT, int n){
  __shared__ short lds[128 * 72];
  int t = threadIdx.x;
  int node0 = blockIdx.x * 64;
  int nl = t >> 2;
  int f0 = (t & 3) * 32;
  int node = node0 + nl;
  if (node < n){
    const f32x4* up = (const f32x4*)(u + (size_t)node * 128 + f0);
    float* dst = (f0 < 64) ? (emb + (size_t)node * 64 + f0)
                           : (emb_a + (size_t)node * 64 + (f0 - 64));
    #pragma unroll
    for (int j4 = 0; j4 < 8; ++j4){
      f32x4 v = up[j4];
      #pragma unroll
      for (int e = 0; e < 4; ++e){
        float x = v[e] > 0.0f ? v[e] : 0.0f;
        v[e] = x;
        lds[(f0 + j4 * 4 + e) * 72 + nl] = f2bf(x);
      }
      ((f32x4*)dst)[j4] = v;
    }
  }
  __syncthreads();
  int f = t >> 1, c0 = (t & 1) * 32;
  short* op = embBT + (size_t)f * n + node0 + c0;
  const short* lp = lds + f * 72 + c0;
  if (node0 + 64 <= n){
    #pragma unroll
    for (int j = 0; j < 4; ++j)
      *(s16x8*)(op + j * 8) = *(const s16x8*)(lp + j * 8);
  } else {
    for (int j = 0; j < 32; ++j)
      if (node0 + c0 + j < n) op[j] = lp[j];
  }
}

// ---------------- readout GEMM: vsumP[ks][n/2][128] u32 (bf16 row-pairs) ----------------
// BARRIER-FREE single-wave blocks: 1 wave = 32 rows x 128 cols, private LDS, depth-3
// global_load_lds pipeline with counted vmcnt(24/12/0). No s_barrier in the loop —
// per-wave in-order waitcnt semantics replace the 2-barrier lockstep (round-15 tax).
// A (HBM mask) read once; B re-staged per wave (extra ~600MB L2 reads, off the HBM path).

__global__ __launch_bounds__(64) void readout_kernel(const float* __restrict__ mask,
    const short* __restrict__ embBT, unsigned* __restrict__ vsumP, int n){
  __shared__ float Ab[3][32][32];    // 12 KB
  __shared__ short Bb[3][128][32];   // 24 KB  (36 KB total -> 4 blocks/CU)
  int l = threadIdx.x, lr = l & 15, g = l >> 4;
  int row0 = blockIdx.x * 32;
  int ks = blockIdx.y;

  int steps_total = (n + 31) >> 5;               // 313
  int per = steps_total / KSPLIT, rem = steps_total % KSPLIT;
  int sbeg = ks * per + (ks < rem ? ks : rem);
  int scnt = per + (ks < rem ? 1 : 0);
  bool tail = ((sbeg + scnt) == steps_total) && ((n & 31) != 0);
  int nf = scnt - (tail ? 1 : 0);
  int kb0 = sbeg << 5;

  // staging sources: linear LDS dest (lane*16B), source chunk pre-XOR'd (rule 21)
  int aswz = ((l & 7) ^ ((l >> 3) & 7)) << 2;                 // float offset
  const float* asrc[4];
  #pragma unroll
  for (int j = 0; j < 4; ++j){
    int ar = row0 + j * 8 + (l >> 3);
    asrc[j] = mask + (size_t)min(ar, n - 1) * n + aswz;
  }
  int bswz = ((l & 3) ^ ((l >> 3) & 3)) << 3;                 // short offset
  const short* bsrc[8];
  #pragma unroll
  for (int j = 0; j < 8; ++j)
    bsrc[j] = embBT + (size_t)(j * 16 + (l >> 2)) * n + bswz;

  #define GLDS(gp, lp) __builtin_amdgcn_global_load_lds( \
      (const __attribute__((address_space(1))) void*)(const void*)(gp), \
      (__attribute__((address_space(3))) void*)(void*)(lp), 16, 0, 0)
  #define STAGE(kb, bi) do{ \
    GLDS(asrc[0] + (kb), &Ab[bi][ 0][0]); \
    GLDS(asrc[1] + (kb), &Ab[bi][ 8][0]); \
    GLDS(asrc[2] + (kb), &Ab[bi][16][0]); \
    GLDS(asrc[3] + (kb), &Ab[bi][24][0]); \
    GLDS(bsrc[0] + (kb), &Bb[bi][  0][0]); \
    GLDS(bsrc[1] + (kb), &Bb[bi][ 16][0]); \
    GLDS(bsrc[2] + (kb), &Bb[bi][ 32][0]); \
    GLDS(bsrc[3] + (kb), &Bb[bi][ 48][0]); \
    GLDS(bsrc[4] + (kb), &Bb[bi][ 64][0]); \
    GLDS(bsrc[5] + (kb), &Bb[bi][ 80][0]); \
    GLDS(bsrc[6] + (kb), &Bb[bi][ 96][0]); \
    GLDS(bsrc[7] + (kb), &Bb[bi][112][0]); \
  }while(0)

  f32x4 acc[2][8];
  #pragma unroll
  for (int rt = 0; rt < 2; ++rt)
    #pragma unroll
    for (int ct = 0; ct < 8; ++ct) acc[rt][ct] = (f32x4){0,0,0,0};

  if (nf > 0) STAGE(kb0, 0);
  if (nf > 1) STAGE(kb0 + 32, 1);
  if (nf > 2) STAGE(kb0 + 64, 2);

  int cur = 0;
  for (int s = 0; s < nf; ++s){
    if (s + 3 <= nf)      asm volatile("s_waitcnt vmcnt(24)" ::: "memory");
    else if (s + 2 == nf) asm volatile("s_waitcnt vmcnt(12)" ::: "memory");
    else                  asm volatile("s_waitcnt vmcnt(0)" ::: "memory");
    s16x8 bfr[8];
    #pragma unroll
    for (int ct = 0; ct < 8; ++ct)
      bfr[ct] = *(const s16x8*)&Bb[cur][ct * 16 + lr][(g ^ ((lr >> 1) & 3)) << 3];
    #pragma unroll
    for (int rt = 0; rt < 2; ++rt){
      f32x4 x0 = *(const f32x4*)&Ab[cur][rt * 16 + lr][((2 * g)     ^ (lr & 7)) << 2];
      f32x4 x1 = *(const f32x4*)&Ab[cur][rt * 16 + lr][((2 * g + 1) ^ (lr & 7)) << 2];
      FragU af;
      af.u[0] = pack_trunc(x0[0], x0[1]); af.u[1] = pack_trunc(x0[2], x0[3]);
      af.u[2] = pack_trunc(x1[0], x1[1]); af.u[3] = pack_trunc(x1[2], x1[3]);
      #pragma unroll
      for (int ct = 0; ct < 8; ++ct)
        acc[rt][ct] = __builtin_amdgcn_mfma_f32_16x16x32_bf16(af.s, bfr[ct], acc[rt][ct], 0, 0, 0);
    }
    // drain this buffer's ds_reads before its gload_lds overwrite (same-wave ordering)
    asm volatile("s_waitcnt lgkmcnt(0)" ::: "memory");
    if (s + 3 < nf) STAGE(kb0 + (s + 3) * 32, cur);
    cur = (cur == 2) ? 0 : cur + 1;
  }
  #undef STAGE
  #undef GLDS

  if (tail){
    int kb = kb0 + nf * 32;
    int kleft = n - kb;                          // 16
    const s16x8 bz = {0,0,0,0,0,0,0,0};
    s16x8 bfr[8];
    #pragma unroll
    for (int ct = 0; ct < 8; ++ct)
      bfr[ct] = (g * 8 < kleft) ? *(const s16x8*)(embBT + (size_t)(ct * 16 + lr) * n + kb + g * 8) : bz;
    #pragma unroll
    for (int rt = 0; rt < 2; ++rt){
      FragU af; af.u = (u32x4){0,0,0,0};
      int r = row0 + rt * 16 + lr;
      if (g * 8 < kleft && r < n){
        const f32x4* p = (const f32x4*)(mask + (size_t)r * n + kb + g * 8);
        f32x4 r0 = p[0], r1 = p[1];
        af.u[0] = pack_trunc(r0[0], r0[1]); af.u[1] = pack_trunc(r0[2], r0[3]);
        af.u[2] = pack_trunc(r1[0], r1[1]); af.u[3] = pack_trunc(r1[2], r1[3]);
      }
      #pragma unroll
      for (int ct = 0; ct < 8; ++ct)
        acc[rt][ct] = __builtin_amdgcn_mfma_f32_16x16x32_bf16(af.s, bfr[ct], acc[rt][ct], 0, 0, 0);
    }
  }

  // epilogue: bf16 row-pair pack (rows g*4+i, g*4+i+1 live in the same lane)
  unsigned* vs = vsumP + (size_t)ks * (n >> 1) * 128;
  #pragma unroll
  for (int rt = 0; rt < 2; ++rt){
    int rbase = row0 + rt * 16;
    #pragma unroll
    for (int ct = 0; ct < 8; ++ct)
      #pragma unroll
      for (int i = 0; i < 4; i += 2){
        int gr = rbase + g * 4 + i;              // even; n even
        if (gr < n)
          vs[(size_t)(gr >> 1) * 128 + ct * 16 + lr] = pack_rtne(acc[rt][ct][i], acc[rt][ct][i + 1]);
      }
  }
}

// ---------------- fused: g = sigmoid(v/||v||) (bf16 K-split sum) + bilinear discriminator ----------------

__global__ __launch_bounds__(256) void gnorm_disc_kernel(const unsigned* __restrict__ vsumP,
    const float* __restrict__ emb, const float* __restrict__ emb_a,
    const float* __restrict__ Wb, const float* __restrict__ bptr,
    float* __restrict__ ret, float* __restrict__ reta, int n){
  __shared__ float Wl[64][65];
  int t = threadIdx.x;
  for (int i = t; i < 4096; i += 256) Wl[i >> 6][i & 63] = Wb[i];
  __syncthreads();
  int wid = t >> 6, lane = t & 63;
  int node = blockIdx.x * 4 + wid;
  if (node >= n) return;

  size_t stride = (size_t)(n >> 1) * 128;
  size_t rowoff = (size_t)(node >> 1) * 128;
  bool hi = (node & 1) != 0;
  float v1 = 0.0f, v2 = 0.0f;
  #pragma unroll
  for (int ks = 0; ks < KSPLIT; ++ks){
    unsigned a = vsumP[ks * stride + rowoff + lane];
    unsigned b = vsumP[ks * stride + rowoff + 64 + lane];
    v1 += hi ? bf_hi(a) : bf_lo(a);
    v2 += hi ? bf_hi(b) : bf_lo(b);
  }
  float s1 = v1 * v1, s2 = v2 * v2;
  for (int off = 32; off >= 1; off >>= 1){
    s1 += __shfl_xor(s1, off);
    s2 += __shfl_xor(s2, off);
  }
  float i1 = v1 / fmaxf(sqrtf(s1), 1e-12f);
  float i2 = v2 / fmaxf(sqrtf(s2), 1e-12f);
  float g1 = 1.0f / (1.0f + expf(-i1));
  float g2 = 1.0f / (1.0f + expf(-i2));

  float e1 = emb[(size_t)node * 64 + lane];
  float e2 = emb_a[(size_t)node * 64 + lane];
  float u1 = 0.0f, u2 = 0.0f;
  for (int e = 0; e < 64; ++e){
    float wv = Wl[lane][e];
    u1 += wv * __shfl(g1, e);
    u2 += wv * __shfl(g2, e);
  }
  float p1 = e1 * u1, p2 = e2 * u1, p3 = e2 * u2, p4 = e1 * u2;
  for (int off = 32; off >= 1; off >>= 1){
    p1 += __shfl_xor(p1, off); p2 += __shfl_xor(p2, off);
    p3 += __shfl_xor(p3, off); p4 += __shfl_xor(p4, off);
  }
  if (lane == 0){
    float b = bptr[0];
    ret[(size_t)node * 2 + 0]  = p1 + b;
    ret[(size_t)node * 2 + 1]  = p2 + b;
    reta[(size_t)node * 2 + 0] = p3 + b;
    reta[(size_t)node * 2 + 1] = p4 + b;
  }
}

// ---------------- launch ----------------

extern "C" void kernel_launch(void* const* d_in, const int* in_sizes, int n_in,
                              void* d_out, int out_size, void* d_ws, size_t ws_size,
                              hipStream_t stream) {
  const float* feat   = (const float*)d_in[0];
  const float* feat_a = (const float*)d_in[1];
  const int*   ei     = (const int*)d_in[2];
  const float* mask   = (const float*)d_in[3];
  const float* W      = (const float*)d_in[4];
  const float* Wb     = (const float*)d_in[5];
  const float* bsc    = (const float*)d_in[6];
  const int n = in_sizes[0] / F_IN;      // 10000
  const int E = in_sizes[2] / 2;         // 640000
  const size_t sl128 = (size_t)n * 128;

  float* out  = (float*)d_out;
  float* ret  = out + (size_t)n * F_OUT;
  float* reta = ret + (size_t)n * 2;

  char* wsb = (char*)d_ws;
  size_t off = 0;
  #define WSALLOC(ptr, T, cnt) T* ptr = (T*)(wsb + off); off = (off + sizeof(T)*(size_t)(cnt) + 255) & ~(size_t)255
  WSALLOC(deg, int, n);
  WSALLOC(counts, int, n);
  WSALLOC(offs, int, n + 1);
  WSALLOC(dis, float, n);
  WSALLOC(selfnorm, float, n);
  WSALLOC(csr, unsigned, E);
  WSALLOC(blkcntP, unsigned, (size_t)HBLK * n);
  WSALLOC(blkbase, int, (size_t)HBLK * n);
  WSALLOC(WT, short, 5 * 64 * 256);
  WSALLOC(Yc0, float, sl128);
  WSALLOC(YcB, unsigned, (size_t)3 * (n >> 1) * 128);
  WSALLOC(t0bf, short, sl128);
  WSALLOC(tb0, unsigned, (size_t)n * 64);
  WSALLOC(tb1, unsigned, (size_t)n * 64);
  WSALLOC(u1, float, sl128);
  WSALLOC(emb_a, float, (size_t)n * F_OUT);
  WSALLOC(embBT, short, (size_t)128 * n);
  WSALLOC(vsumP, unsigned, (size_t)KSPLIT * (n >> 1) * 128);
  (void)ws_size; (void)n_in; (void)out_size;

  wt_kernel<<<(5 * 64 * 256 + 255) / 256, 256, 0, stream>>>(W, WT);
  hist_kernel<<<HBLK, 1024, 0, stream>>>(ei, E, blkcntP, n);
  sumcnt_kernel<<<(n + 255) / 256, 256, 0, stream>>>(blkcntP, counts, deg, n);
  scan_kernel<<<1, 1024, 0, stream>>>(counts, deg, dis, selfnorm, offs, n);
  blkbase_kernel<<<(n + 255) / 256, 256, 0, stream>>>(offs, blkcntP, blkbase, n);
  fill_kernel<<<HBLK, 1024, 0, stream>>>(ei, E, dis, blkbase, csr, n);

  fgemm_kernel<<<dim3(n / 16, 2), 320, 0, stream>>>(feat, feat_a, WT, Yc0, YcB, t0bf, n);

  int gb = (n + 3) / 4;
  const size_t ybs = (size_t)(n >> 1) * 128;
  // Horner: u = slab4(t0bf); u = slab3 + A u; u = slab2 + A u; u = slab1 + A u; u = slab0 + A u
  gather_kernel<<<gb, 256, 0, stream>>>(YcB + 2 * ybs, (unsigned*)t0bf, offs, csr, selfnorm, tb0, (float*)0, n, 0, 1);
  gather_kernel<<<gb, 256, 0, stream>>>(YcB + 1 * ybs, tb0, offs, csr, selfnorm, tb1, (float*)0, n, 0, 1);
  gather_kernel<<<gb, 256, 0, stream>>>(YcB + 0 * ybs, tb1, offs, csr, selfnorm, tb0, (float*)0, n, 0, 1);
  gather_kernel<<<gb, 256, 0, stream>>>(Yc0, tb0, offs, csr, selfnorm, (unsigned*)0, u1, n, 1, 0);
  relu_trans_kernel<<<(n + 63) / 64, 256, 0, stream>>>(u1, out, emb_a, embBT, n);

  readout_kernel<<<dim3((n + 31) / 32, KSPLIT), 64, 0, stream>>>(mask, embBT, vsumP, n);
  gnorm_disc_kernel<<<gb, 256, 0, stream>>>(vsumP, out, emb_a, Wb, bsc, ret, reta, n);
}

// Round 17
// 295.324 us; speedup vs baseline: 1.2303x; 1.2303x over previous
//
#include <hip/hip_runtime.h>
#include <hip/hip_bf16.h>
#include <hip/hip_fp16.h>

typedef float f32x4 __attribute__((ext_vector_type(4)));
typedef short s16x8 __attribute__((ext_vector_type(8)));
typedef unsigned int u32x4 __attribute__((ext_vector_type(4)));

#define F_IN 256
#define F_OUT 64
#define KSPLIT 9
#define HBLK 120

static __device__ __forceinline__ short f2bf(float f){  // RTNE
  union { float f; unsigned u; } x; x.f = f;
  unsigned r = (x.u + 0x7FFFu + ((x.u >> 16) & 1u)) >> 16;
  return (short)r;
}

static __device__ __forceinline__ unsigned pack_rtne(float f0, float f1){
  return ((unsigned)(unsigned short)f2bf(f0)) | ((unsigned)(unsigned short)f2bf(f1) << 16);
}

// truncation pack (bias cancels in L2-normalize downstream of the mask GEMM)
static __device__ __forceinline__ unsigned pack_trunc(float f0, float f1){
  return (__float_as_uint(f0) >> 16) | (__float_as_uint(f1) & 0xFFFF0000u);
}

static __device__ __forceinline__ float bf_lo(unsigned u){ return __uint_as_float(u << 16); }
static __device__ __forceinline__ float bf_hi(unsigned u){ return __uint_as_float(u & 0xFFFF0000u); }
static __device__ __forceinline__ float h16(unsigned u){   // fp16 in high16 -> f32
  return __half2float(__ushort_as_half((unsigned short)(u >> 16)));
}

union FragU { u32x4 u; s16x8 s; };

// ---------------- WT transpose-cast ----------------

__global__ void wt_kernel(const float* __restrict__ W, short* __restrict__ WT){
  int idx = blockIdx.x * blockDim.x + threadIdx.x;
  if (idx < 5 * 64 * 256){
    int k = idx & 255, c = (idx >> 8) & 63, by = idx >> 14;
    WT[idx] = f2bf(W[(size_t)(by * 256 + k) * 64 + c]);
  }
}

// ---------------- histogram: single pass, packed LDS bins (lo16=col, hi16=row) ----------------
// per-block count <= ceil(E/HBLK)=5334 < 2^16. NO global atomics: coalesced blkcntP store only.

__global__ __launch_bounds__(1024) void hist_kernel(const int* __restrict__ ei, int E,
                                                    unsigned* __restrict__ blkcntP, int n){
  __shared__ unsigned bins[10240];   // 40 KB
  int tid = threadIdx.x;
  int per = (E + HBLK - 1) / HBLK;
  int e0 = blockIdx.x * per, e1 = min(E, e0 + per);

  for (int i = tid; i < n; i += 1024) bins[i] = 0u;
  __syncthreads();
  for (int e = e0 + tid; e < e1; e += 1024){
    int r = ei[e], c = ei[E + e];
    if (r != c){
      atomicAdd(&bins[c], 1u);
      atomicAdd(&bins[r], 0x10000u);
    }
  }
  __syncthreads();
  for (int i = tid; i < n; i += 1024)
    blkcntP[(size_t)blockIdx.x * n + i] = bins[i];
}

// ---------------- per-bin totals from blkcntP (coalesced; plain stores) ----------------

__global__ void sumcnt_kernel(const unsigned* __restrict__ blkcntP,
                              int* __restrict__ counts, int* __restrict__ deg, int n){
  int bin = blockIdx.x * blockDim.x + threadIdx.x;
  if (bin >= n) return;
  int cc = 0, rc = 0;
  #pragma unroll 8
  for (int blk = 0; blk < HBLK; ++blk){
    unsigned v = blkcntP[(size_t)blk * n + bin];
    cc += (int)(v & 0xFFFFu);
    rc += (int)(v >> 16);
  }
  counts[bin] = cc;
  deg[bin] = rc;
}

// ---------------- scan (wave-shuffle, 4 barriers) + dis/selfnorm ----------------

__global__ __launch_bounds__(1024) void scan_kernel(const int* __restrict__ counts,
                                                    const int* __restrict__ deg,
                                                    float* __restrict__ dis,
                                                    float* __restrict__ selfnorm,
                                                    int* __restrict__ offsets, int n){
  const int C = 10;
  __shared__ int vals[10240];   // 40 KB
  __shared__ int wsums[16];
  int tid = threadIdx.x, wid = tid >> 6, lane = tid & 63;
  for (int i = tid; i < 10240; i += 1024) vals[i] = (i < n) ? counts[i] : 0;
  for (int i = tid; i < n; i += 1024){
    float d = (float)(deg[i] + 1);   // +1: appended self-loop
    dis[i] = rsqrtf(d);
    selfnorm[i] = 1.0f / d;
  }
  __syncthreads();
  int base = tid * C;
  int s = 0;
  #pragma unroll
  for (int i = 0; i < C; ++i) s += vals[base + i];
  int x = s;
  #pragma unroll
  for (int off = 1; off < 64; off <<= 1){
    int y = __shfl_up(x, off);
    if (lane >= off) x += y;
  }
  if (lane == 63) wsums[wid] = x;
  __syncthreads();
  if (wid == 0){
    int v = (lane < 16) ? wsums[lane] : 0;
    int xx = v;
    #pragma unroll
    for (int off = 1; off < 16; off <<= 1){
      int y = __shfl_up(xx, off);
      if (lane >= off) xx += y;
    }
    if (lane < 16) wsums[lane] = xx - v;   // exclusive wave prefix
  }
  __syncthreads();
  int run = (x - s) + wsums[wid];          // exclusive thread prefix
  if (tid == 1023) offsets[n] = run + s;   // grand total
  #pragma unroll
  for (int i = 0; i < C; ++i){ int v = vals[base + i]; vals[base + i] = run; run += v; }
  __syncthreads();
  for (int i = tid; i < 10240; i += 1024)
    if (i < n) offsets[i] = vals[i];
}

// ---------------- per-(block,bin) base positions (unrolled: 8 loads in flight) ----------------

__global__ void blkbase_kernel(const int* __restrict__ offsets, const unsigned* __restrict__ blkcntP,
                               int* __restrict__ blkbase, int n){
  int bin = blockIdx.x * blockDim.x + threadIdx.x;
  if (bin >= n) return;
  int run = offsets[bin];
  #pragma unroll 8
  for (int blk = 0; blk < HBLK; ++blk){
    blkbase[(size_t)blk * n + bin] = run;
    run += (int)(blkcntP[(size_t)blk * n + bin] & 0xFFFFu);
  }
}

// ---------------- fill via LDS cursors (zero global atomics) ----------------
// packed CSR entry: row (u16) | fp16(norm) << 16. Edge ranges match hist_kernel.

__global__ __launch_bounds__(1024) void fill_kernel(const int* __restrict__ ei, int E,
                                                    const float* __restrict__ dis,
                                                    const int* __restrict__ blkbase,
                                                    unsigned* __restrict__ csr, int n){
  __shared__ int bins[10240];   // 40 KB
  int tid = threadIdx.x;
  int per = (E + HBLK - 1) / HBLK;
  int e0 = blockIdx.x * per, e1 = min(E, e0 + per);
  for (int i = tid; i < n; i += 1024) bins[i] = blkbase[(size_t)blockIdx.x * n + i];
  __syncthreads();
  for (int e = e0 + tid; e < e1; e += 1024){
    int r = ei[e], c = ei[E + e];
    if (r == c) continue;
    int pos = atomicAdd(&bins[c], 1);
    unsigned h = (unsigned)__half_as_ushort(__float2half(dis[r] * dis[c]));
    csr[pos] = (unsigned)r | (h << 16);
  }
}

// ---------------- feature GEMM: 5 waves/block, X-strip staged to LDS once ----------------

__global__ __launch_bounds__(320) void fgemm_kernel(const float* __restrict__ X0,
                                                    const float* __restrict__ X1,
                                                    const short* __restrict__ WT,
                                                    float* __restrict__ Yc0,
                                                    unsigned* __restrict__ YcB,
                                                    short* __restrict__ t0bf, int M){
  __shared__ float Xs[16][260];
  int tid = threadIdx.x;
  int w = tid >> 6, l = tid & 63, lr = l & 15, g = l >> 4;
  int row0 = blockIdx.x * 16, bz = blockIdx.y;
  const float* X = bz ? X1 : X0;
  for (int i = tid; i < 1024; i += 320){
    int r = i >> 6, c4 = (i & 63) << 2;
    *(f32x4*)&Xs[r][c4] = *(const f32x4*)(X + (size_t)(row0 + r) * F_IN + c4);
  }
  __syncthreads();

  s16x8 afr[8];
  #pragma unroll
  for (int it = 0; it < 8; ++it){
    f32x4 x0 = *(const f32x4*)&Xs[lr][it * 32 + g * 8];
    f32x4 x1 = *(const f32x4*)&Xs[lr][it * 32 + g * 8 + 4];
    FragU af;
    af.u[0] = pack_rtne(x0[0], x0[1]); af.u[1] = pack_rtne(x0[2], x0[3]);
    af.u[2] = pack_rtne(x1[0], x1[1]); af.u[3] = pack_rtne(x1[2], x1[3]);
    afr[it] = af.s;
  }

  int by = w;   // wave = slab
  f32x4 acc[4];
  #pragma unroll
  for (int ct = 0; ct < 4; ++ct) acc[ct] = (f32x4){0,0,0,0};
  const s16x8* bp[4];
  #pragma unroll
  for (int ct = 0; ct < 4; ++ct)
    bp[ct] = (const s16x8*)(WT + ((size_t)by * 64 + ct * 16 + lr) * F_IN + g * 8);
  #pragma unroll
  for (int it = 0; it < 8; ++it)
    #pragma unroll
    for (int ct = 0; ct < 4; ++ct)
      acc[ct] = __builtin_amdgcn_mfma_f32_16x16x32_bf16(afr[it], bp[ct][it * 4], acc[ct], 0, 0, 0);

  if (by == 0){
    float* yp = Yc0 + (size_t)bz * 64;
    #pragma unroll
    for (int ct = 0; ct < 4; ++ct)
      #pragma unroll
      for (int i = 0; i < 4; ++i)
        yp[(size_t)(row0 + g * 4 + i) * 128 + ct * 16 + lr] = acc[ct][i];
  } else if (by <= 3){
    unsigned* yb = YcB + (size_t)(by - 1) * (M >> 1) * 128 + (size_t)bz * 64;
    #pragma unroll
    for (int ct = 0; ct < 4; ++ct)
      #pragma unroll
      for (int i = 0; i < 4; i += 2){
        int grow = row0 + g * 4 + i;   // even
        yb[(size_t)(grow >> 1) * 128 + ct * 16 + lr] = pack_rtne(acc[ct][i], acc[ct][i + 1]);
      }
  } else {
    short* tb = t0bf + (size_t)bz * 64;
    #pragma unroll
    for (int ct = 0; ct < 4; ++ct)
      #pragma unroll
      for (int i = 0; i < 4; ++i)
        tb[(size_t)(row0 + g * 4 + i) * 128 + ct * 16 + lr] = f2bf(acc[ct][i]);
  }
}

// ---------------- sparse propagate (bf16 messages, packed CSR): tout = Yk + A * tin ----------------
// 8-way unrolled edge loop: 8 L2 gathers in flight per wave.

__global__ __launch_bounds__(256) void gather_kernel(const void* __restrict__ Yk,
    const unsigned* __restrict__ tinb, const int* __restrict__ offsets,
    const unsigned* __restrict__ csr, const float* __restrict__ selfnorm,
    unsigned* __restrict__ toutb, float* __restrict__ toutf, int n, int wantf, int ykbf){
  int wid = threadIdx.x >> 6, lane = threadIdx.x & 63;
  int node = blockIdx.x * 4 + wid;
  if (node >= n) return;
  int e0 = offsets[node], e1 = offsets[node + 1];
  float sn = selfnorm[node];
  unsigned t0 = tinb[(size_t)node * 64 + lane];
  float ykx, yky;
  if (ykbf){
    const unsigned* yp = (const unsigned*)Yk + (size_t)(node >> 1) * 128 + lane * 2;
    unsigned u0 = yp[0], u1 = yp[1];
    if (node & 1){ ykx = bf_hi(u0); yky = bf_hi(u1); }
    else         { ykx = bf_lo(u0); yky = bf_lo(u1); }
  } else {
    float2 yk = ((const float2*)Yk)[(size_t)node * 64 + lane];
    ykx = yk.x; yky = yk.y;
  }
  float ax = ykx + sn * bf_lo(t0);
  float ay = yky + sn * bf_hi(t0);
  int i = e0;
  for (; i + 8 <= e1; i += 8){
    unsigned q0 = csr[i],   q1 = csr[i+1], q2 = csr[i+2], q3 = csr[i+3];
    unsigned q4 = csr[i+4], q5 = csr[i+5], q6 = csr[i+6], q7 = csr[i+7];
    unsigned v0 = tinb[(size_t)(q0 & 0xFFFFu) * 64 + lane];
    unsigned v1 = tinb[(size_t)(q1 & 0xFFFFu) * 64 + lane];
    unsigned v2 = tinb[(size_t)(q2 & 0xFFFFu) * 64 + lane];
    unsigned v3 = tinb[(size_t)(q3 & 0xFFFFu) * 64 + lane];
    unsigned v4 = tinb[(size_t)(q4 & 0xFFFFu) * 64 + lane];
    unsigned v5 = tinb[(size_t)(q5 & 0xFFFFu) * 64 + lane];
    unsigned v6 = tinb[(size_t)(q6 & 0xFFFFu) * 64 + lane];
    unsigned v7 = tinb[(size_t)(q7 & 0xFFFFu) * 64 + lane];
    float w0 = h16(q0), w1 = h16(q1), w2 = h16(q2), w3 = h16(q3);
    float w4 = h16(q4), w5 = h16(q5), w6 = h16(q6), w7 = h16(q7);
    ax += w0 * bf_lo(v0); ay += w0 * bf_hi(v0);
    ax += w1 * bf_lo(v1); ay += w1 * bf_hi(v1);
    ax += w2 * bf_lo(v2); ay += w2 * bf_hi(v2);
    ax += w3 * bf_lo(v3); ay += w3 * bf_hi(v3);
    ax += w4 * bf_lo(v4); ay += w4 * bf_hi(v4);
    ax += w5 * bf_lo(v5); ay += w5 * bf_hi(v5);
    ax += w6 * bf_lo(v6); ay += w6 * bf_hi(v6);
    ax += w7 * bf_lo(v7); ay += w7 * bf_hi(v7);
  }
  for (; i + 4 <= e1; i += 4){
    unsigned q0 = csr[i], q1 = csr[i+1], q2 = csr[i+2], q3 = csr[i+3];
    unsigned v0 = tinb[(size_t)(q0 & 0xFFFFu) * 64 + lane];
    unsigned v1 = tinb[(size_t)(q1 & 0xFFFFu) * 64 + lane];
    unsigned v2 = tinb[(size_t)(q2 & 0xFFFFu) * 64 + lane];
    unsigned v3 = tinb[(size_t)(q3 & 0xFFFFu) * 64 + lane];
    float w0 = h16(q0), w1 = h16(q1), w2 = h16(q2), w3 = h16(q3);
    ax += w0 * bf_lo(v0); ay += w0 * bf_hi(v0);
    ax += w1 * bf_lo(v1); ay += w1 * bf_hi(v1);
    ax += w2 * bf_lo(v2); ay += w2 * bf_hi(v2);
    ax += w3 * bf_lo(v3); ay += w3 * bf_hi(v3);
  }
  for (; i < e1; ++i){
    unsigned q = csr[i];
    float w = h16(q);
    unsigned v = tinb[(size_t)(q & 0xFFFFu) * 64 + lane];
    ax += w * bf_lo(v); ay += w * bf_hi(v);
  }
  if (wantf){
    float2 r; r.x = ax; r.y = ay;
    ((float2*)toutf)[(size_t)node * 64 + lane] = r;
  } else {
    toutb[(size_t)node * 64 + lane] = pack_rtne(ax, ay);
  }
}

// ---------------- relu + split + LDS-transpose bf16 pack ----------------

__global__ __launch_bounds__(256) void relu_trans_kernel(const float* __restrict__ u,
    float* __restrict__ emb, float* __restrict__ emb_a, short* __restrict__ embBT, int n){
  __shared__ short lds[128 * 72];
  int t = threadIdx.x;
  int node0 = blockIdx.x * 64;
  int nl = t >> 2;
  int f0 = (t & 3) * 32;
  int node = node0 + nl;
  if (node < n){
    const f32x4* up = (const f32x4*)(u + (size_t)node * 128 + f0);
    float* dst = (f0 < 64) ? (emb + (size_t)node * 64 + f0)
                           : (emb_a + (size_t)node * 64 + (f0 - 64));
    #pragma unroll
    for (int j4 = 0; j4 < 8; ++j4){
      f32x4 v = up[j4];
      #pragma unroll
      for (int e = 0; e < 4; ++e){
        float x = v[e] > 0.0f ? v[e] : 0.0f;
        v[e] = x;
        lds[(f0 + j4 * 4 + e) * 72 + nl] = f2bf(x);
      }
      ((f32x4*)dst)[j4] = v;
    }
  }
  __syncthreads();
  int f = t >> 1, c0 = (t & 1) * 32;
  short* op = embBT + (size_t)f * n + node0 + c0;
  const short* lp = lds + f * 72 + c0;
  if (node0 + 64 <= n){
    #pragma unroll
    for (int j = 0; j < 4; ++j)
      *(s16x8*)(op + j * 8) = *(const s16x8*)(lp + j * 8);
  } else {
    for (int j = 0; j < 32; ++j)
      if (node0 + c0 + j < n) op[j] = lp[j];
  }
}

// ---------------- readout GEMM: vsumP[ks][n/2][128] u32 (bf16 row-pairs) ----------------
// BM=128 (wave = 32 rows x 128 cols, B frags reg-cached across row-tiles).
// global_load_lds depth-2, counted vmcnt(6), chunk-XOR swizzle (rule 21).
// Best-measured readout structure (round 15); structural variants (depth-3,
// barrier-free single-wave, reg-prefetch) all null or regressed.

__global__ __launch_bounds__(256, 3) void readout_kernel(const float* __restrict__ mask,
    const short* __restrict__ embBT, unsigned* __restrict__ vsumP, int n){
  __shared__ float Ab[2][128][32];   // 32 KB
  __shared__ short Bb[2][128][32];   // 16 KB
  int t = threadIdx.x;
  int w = t >> 6, l = t & 63, lr = l & 15, g = l >> 4;
  int row0 = blockIdx.x * 128;
  int ks = blockIdx.y;

  int steps_total = (n + 31) >> 5;               // 313
  int per = steps_total / KSPLIT, rem = steps_total % KSPLIT;
  int sbeg = ks * per + (ks < rem ? ks : rem);
  int scnt = per + (ks < rem ? 1 : 0);
  bool tail = ((sbeg + scnt) == steps_total) && ((n & 31) != 0);
  int nf = scnt - (tail ? 1 : 0);
  int kb0 = sbeg << 5;

  // staging sources: linear LDS dest (wave-uniform base + lane*16B), source chunk pre-XOR'd
  int aswz = ((l & 7) ^ ((l >> 3) & 7)) << 2;                 // float offset
  const float* asrc[4];
  #pragma unroll
  for (int j = 0; j < 4; ++j){
    int ar = row0 + w * 32 + j * 8 + (l >> 3);
    asrc[j] = mask + (size_t)min(ar, n - 1) * n + aswz;
  }
  int bcol = w * 32 + (l >> 2);
  int bswz = ((l & 3) ^ ((l >> 3) & 3)) << 3;                 // short offset
  const short* bsrc0 = embBT + (size_t)bcol * n + bswz;
  const short* bsrc1 = embBT + (size_t)(bcol + 16) * n + bswz;

  #define GLDS(gp, lp) __builtin_amdgcn_global_load_lds( \
      (const __attribute__((address_space(1))) void*)(const void*)(gp), \
      (__attribute__((address_space(3))) void*)(void*)(lp), 16, 0, 0)
  #define STAGE(kb, bi) do{ \
    GLDS(asrc[0] + (kb), &Ab[bi][w * 32     ][0]); \
    GLDS(asrc[1] + (kb), &Ab[bi][w * 32 +  8][0]); \
    GLDS(asrc[2] + (kb), &Ab[bi][w * 32 + 16][0]); \
    GLDS(asrc[3] + (kb), &Ab[bi][w * 32 + 24][0]); \
    GLDS(bsrc0 + (kb), &Bb[bi][w * 32     ][0]); \
    GLDS(bsrc1 + (kb), &Bb[bi][w * 32 + 16][0]); \
  }while(0)

  f32x4 acc[2][8];
  #pragma unroll
  for (int rt = 0; rt < 2; ++rt)
    #pragma unroll
    for (int ct = 0; ct < 8; ++ct) acc[rt][ct] = (f32x4){0,0,0,0};

  if (nf > 0) STAGE(kb0, 0);
  if (nf > 1) STAGE(kb0 + 32, 1);

  for (int s = 0; s < nf; ++s){
    if (s + 1 < nf) asm volatile("s_waitcnt vmcnt(6)" ::: "memory");
    else            asm volatile("s_waitcnt vmcnt(0)" ::: "memory");
    __builtin_amdgcn_s_barrier();
    int cur = s & 1;
    s16x8 bfr[8];
    #pragma unroll
    for (int ct = 0; ct < 8; ++ct)
      bfr[ct] = *(const s16x8*)&Bb[cur][ct * 16 + lr][(g ^ ((lr >> 1) & 3)) << 3];
    #pragma unroll
    for (int rt = 0; rt < 2; ++rt){
      f32x4 x0 = *(const f32x4*)&Ab[cur][w * 32 + rt * 16 + lr][((2 * g)     ^ (lr & 7)) << 2];
      f32x4 x1 = *(const f32x4*)&Ab[cur][w * 32 + rt * 16 + lr][((2 * g + 1) ^ (lr & 7)) << 2];
      FragU af;
      af.u[0] = pack_trunc(x0[0], x0[1]); af.u[1] = pack_trunc(x0[2], x0[3]);
      af.u[2] = pack_trunc(x1[0], x1[1]); af.u[3] = pack_trunc(x1[2], x1[3]);
      #pragma unroll
      for (int ct = 0; ct < 8; ++ct)
        acc[rt][ct] = __builtin_amdgcn_mfma_f32_16x16x32_bf16(af.s, bfr[ct], acc[rt][ct], 0, 0, 0);
    }
    asm volatile("s_waitcnt lgkmcnt(0)" ::: "memory");
    __builtin_amdgcn_s_barrier();
    if (s + 2 < nf) STAGE(kb0 + (s + 2) * 32, cur);
  }
  #undef STAGE
  #undef GLDS

  if (tail){
    int kb = kb0 + nf * 32;
    int kleft = n - kb;                          // 16
    const s16x8 bz = {0,0,0,0,0,0,0,0};
    s16x8 bfr[8];
    #pragma unroll
    for (int ct = 0; ct < 8; ++ct)
      bfr[ct] = (g * 8 < kleft) ? *(const s16x8*)(embBT + (size_t)(ct * 16 + lr) * n + kb + g * 8) : bz;
    #pragma unroll
    for (int rt = 0; rt < 2; ++rt){
      FragU af; af.u = (u32x4){0,0,0,0};
      int r = row0 + w * 32 + rt * 16 + lr;
      if (g * 8 < kleft && r < n){
        const f32x4* p = (const f32x4*)(mask + (size_t)r * n + kb + g * 8);
        f32x4 r0 = p[0], r1 = p[1];
        af.u[0] = pack_trunc(r0[0], r0[1]); af.u[1] = pack_trunc(r0[2], r0[3]);
        af.u[2] = pack_trunc(r1[0], r1[1]); af.u[3] = pack_trunc(r1[2], r1[3]);
      }
      #pragma unroll
      for (int ct = 0; ct < 8; ++ct)
        acc[rt][ct] = __builtin_amdgcn_mfma_f32_16x16x32_bf16(af.s, bfr[ct], acc[rt][ct], 0, 0, 0);
    }
  }

  // epilogue: bf16 row-pair pack (rows g*4+i, g*4+i+1 live in the same lane)
  unsigned* vs = vsumP + (size_t)ks * (n >> 1) * 128;
  #pragma unroll
  for (int rt = 0; rt < 2; ++rt){
    int rbase = row0 + w * 32 + rt * 16;
    #pragma unroll
    for (int ct = 0; ct < 8; ++ct)
      #pragma unroll
      for (int i = 0; i < 4; i += 2){
        int gr = rbase + g * 4 + i;              // even; n even
        if (gr < n)
          vs[(size_t)(gr >> 1) * 128 + ct * 16 + lr] = pack_rtne(acc[rt][ct][i], acc[rt][ct][i + 1]);
      }
  }
}

// ---------------- fused: g = sigmoid(v/||v||) (bf16 K-split sum) + bilinear discriminator ----------------

__global__ __launch_bounds__(256) void gnorm_disc_kernel(const unsigned* __restrict__ vsumP,
    const float* __restrict__ emb, const float* __restrict__ emb_a,
    const float* __restrict__ Wb, const float* __restrict__ bptr,
    float* __restrict__ ret, float* __restrict__ reta, int n){
  __shared__ float Wl[64][65];
  int t = threadIdx.x;
  for (int i = t; i < 4096; i += 256) Wl[i >> 6][i & 63] = Wb[i];
  __syncthreads();
  int wid = t >> 6, lane = t & 63;
  int node = blockIdx.x * 4 + wid;
  if (node >= n) return;

  size_t stride = (size_t)(n >> 1) * 128;
  size_t rowoff = (size_t)(node >> 1) * 128;
  bool hi = (node & 1) != 0;
  float v1 = 0.0f, v2 = 0.0f;
  #pragma unroll
  for (int ks = 0; ks < KSPLIT; ++ks){
    unsigned a = vsumP[ks * stride + rowoff + lane];
    unsigned b = vsumP[ks * stride + rowoff + 64 + lane];
    v1 += hi ? bf_hi(a) : bf_lo(a);
    v2 += hi ? bf_hi(b) : bf_lo(b);
  }
  float s1 = v1 * v1, s2 = v2 * v2;
  for (int off = 32; off >= 1; off >>= 1){
    s1 += __shfl_xor(s1, off);
    s2 += __shfl_xor(s2, off);
  }
  float i1 = v1 / fmaxf(sqrtf(s1), 1e-12f);
  float i2 = v2 / fmaxf(sqrtf(s2), 1e-12f);
  float g1 = 1.0f / (1.0f + expf(-i1));
  float g2 = 1.0f / (1.0f + expf(-i2));

  float e1 = emb[(size_t)node * 64 + lane];
  float e2 = emb_a[(size_t)node * 64 + lane];
  float u1 = 0.0f, u2 = 0.0f;
  for (int e = 0; e < 64; ++e){
    float wv = Wl[lane][e];
    u1 += wv * __shfl(g1, e);
    u2 += wv * __shfl(g2, e);
  }
  float p1 = e1 * u1, p2 = e2 * u1, p3 = e2 * u2, p4 = e1 * u2;
  for (int off = 32; off >= 1; off >>= 1){
    p1 += __shfl_xor(p1, off); p2 += __shfl_xor(p2, off);
    p3 += __shfl_xor(p3, off); p4 += __shfl_xor(p4, off);
  }
  if (lane == 0){
    float b = bptr[0];
    ret[(size_t)node * 2 + 0]  = p1 + b;
    ret[(size_t)node * 2 + 1]  = p2 + b;
    reta[(size_t)node * 2 + 0] = p3 + b;
    reta[(size_t)node * 2 + 1] = p4 + b;
  }
}

// ---------------- launch ----------------

extern "C" void kernel_launch(void* const* d_in, const int* in_sizes, int n_in,
                              void* d_out, int out_size, void* d_ws, size_t ws_size,
                              hipStream_t stream) {
  const float* feat   = (const float*)d_in[0];
  const float* feat_a = (const float*)d_in[1];
  const int*   ei     = (const int*)d_in[2];
  const float* mask   = (const float*)d_in[3];
  const float* W      = (const float*)d_in[4];
  const float* Wb     = (const float*)d_in[5];
  const float* bsc    = (const float*)d_in[6];
  const int n = in_sizes[0] / F_IN;      // 10000
  const int E = in_sizes[2] / 2;         // 640000
  const size_t sl128 = (size_t)n * 128;

  float* out  = (float*)d_out;
  float* ret  = out + (size_t)n * F_OUT;
  float* reta = ret + (size_t)n * 2;

  char* wsb = (char*)d_ws;
  size_t off = 0;
  #define WSALLOC(ptr, T, cnt) T* ptr = (T*)(wsb + off); off = (off + sizeof(T)*(size_t)(cnt) + 255) & ~(size_t)255
  WSALLOC(deg, int, n);
  WSALLOC(counts, int, n);
  WSALLOC(offs, int, n + 1);
  WSALLOC(dis, float, n);
  WSALLOC(selfnorm, float, n);
  WSALLOC(csr, unsigned, E);
  WSALLOC(blkcntP, unsigned, (size_t)HBLK * n);
  WSALLOC(blkbase, int, (size_t)HBLK * n);
  WSALLOC(WT, short, 5 * 64 * 256);
  WSALLOC(Yc0, float, sl128);
  WSALLOC(YcB, unsigned, (size_t)3 * (n >> 1) * 128);
  WSALLOC(t0bf, short, sl128);
  WSALLOC(tb0, unsigned, (size_t)n * 64);
  WSALLOC(tb1, unsigned, (size_t)n * 64);
  WSALLOC(u1, float, sl128);
  WSALLOC(emb_a, float, (size_t)n * F_OUT);
  WSALLOC(embBT, short, (size_t)128 * n);
  WSALLOC(vsumP, unsigned, (size_t)KSPLIT * (n >> 1) * 128);
  (void)ws_size; (void)n_in; (void)out_size;

  wt_kernel<<<(5 * 64 * 256 + 255) / 256, 256, 0, stream>>>(W, WT);
  hist_kernel<<<HBLK, 1024, 0, stream>>>(ei, E, blkcntP, n);
  sumcnt_kernel<<<(n + 255) / 256, 256, 0, stream>>>(blkcntP, counts, deg, n);
  scan_kernel<<<1, 1024, 0, stream>>>(counts, deg, dis, selfnorm, offs, n);
  blkbase_kernel<<<(n + 255) / 256, 256, 0, stream>>>(offs, blkcntP, blkbase, n);
  fill_kernel<<<HBLK, 1024, 0, stream>>>(ei, E, dis, blkbase, csr, n);

  fgemm_kernel<<<dim3(n / 16, 2), 320, 0, stream>>>(feat, feat_a, WT, Yc0, YcB, t0bf, n);

  int gb = (n + 3) / 4;
  const size_t ybs = (size_t)(n >> 1) * 128;
  // Horner: u = slab4(t0bf); u = slab3 + A u; u = slab2 + A u; u = slab1 + A u; u = slab0 + A u
  gather_kernel<<<gb, 256, 0, stream>>>(YcB + 2 * ybs, (unsigned*)t0bf, offs, csr, selfnorm, tb0, (float*)0, n, 0, 1);
  gather_kernel<<<gb, 256, 0, stream>>>(YcB + 1 * ybs, tb0, offs, csr, selfnorm, tb1, (float*)0, n, 0, 1);
  gather_kernel<<<gb, 256, 0, stream>>>(YcB + 0 * ybs, tb1, offs, csr, selfnorm, tb0, (float*)0, n, 0, 1);
  gather_kernel<<<gb, 256, 0, stream>>>(Yc0, tb0, offs, csr, selfnorm, (unsigned*)0, u1, n, 1, 0);
  relu_trans_kernel<<<(n + 63) / 64, 256, 0, stream>>>(u1, out, emb_a, embBT, n);

  readout_kernel<<<dim3((n + 127) / 128, KSPLIT), 256, 0, stream>>>(mask, embBT, vsumP, n);
  gnorm_disc_kernel<<<gb, 256, 0, stream>>>(vsumP, out, emb_a, Wb, bsc, ret, reta, n);
}